// Round 14
// baseline (163.317 us; speedup 1.0000x reference)
//
#include <hip/hip_runtime.h>
#include <hip/hip_bf16.h>
#include <cstdint>

#define NBATCH 512
#define NDIM   2048
#define NHEADS 16
#define NCPH   128

typedef __bf16 bf16x8 __attribute__((ext_vector_type(8)));
typedef float  f32x4  __attribute__((ext_vector_type(4)));

__device__ __forceinline__ unsigned short f2bf(float f) {
    uint32_t u = __builtin_bit_cast(uint32_t, f);
    u += 0x7FFFu + ((u >> 16) & 1u);   // round-to-nearest-even
    return (unsigned short)(u >> 16);
}

__device__ __forceinline__ void gl_lds16(const void* g, void* l) {
    __builtin_amdgcn_global_load_lds(
        (const __attribute__((address_space(1))) void*)g,
        (__attribute__((address_space(3))) void*)l,
        16, 0, 0);
}

// ---------------- convert Wqv + x -> bf16 (24 MiB out) -----------------
__global__ __launch_bounds__(256) void cvt_wx(
    const float* __restrict__ wqv, const float* __restrict__ x,
    unsigned short* __restrict__ owqv, unsigned short* __restrict__ ox)
{
    const int t = blockIdx.x * 256 + threadIdx.x;
    const int n1 = (2 * NDIM * NDIM) / 4;   // Wqv float4 count
    const float4* src; unsigned short* dst; int idx;
    if (t < n1) { src = (const float4*)wqv; dst = owqv; idx = t; }
    else        { src = (const float4*)x;   dst = ox;   idx = t - n1; }
    float4 v = src[idx];
    ushort4 o;
    o.x = f2bf(v.x); o.y = f2bf(v.y); o.z = f2bf(v.z); o.w = f2bf(v.w);
    *(ushort4*)(dst + (size_t)idx * 4) = o;
}

// ---------------- pure-DMA bf16 GEMM (gemm1) ---------------------------
// C[m,n] = sum_k A[m,k]*B[n,k]; both operands PRE-CONVERTED bf16, staged
// exclusively via global_load_lds (pre-swizzled global src, linear LDS
// dest -- rule #21).  BK=128 -> 16 K-steps.  Step interior = {issue 8
// gl_lds -> 64 MFMA on other buffer -> barrier}: no VALU cvt, no
// ds_write, half the weight bytes of the r13 reg-staged version.  This
// is the one untested combination (r2 = DMA + BK<=64 + 2 barriers;
// r13 = BK=128 + f32 reg-staging).  nb-major grid: XCD = nb%8, the 8
// m-blocks of one n-panel share an XCD -> B streams HBM once.
// BNP: v-half blocks (n0>=NDIM) emit per-tile BN sums (s, ss).
template<int BM, int BN, int BK, bool BNP>
__global__ __launch_bounds__(256) void gemm_dma(
    const unsigned short* __restrict__ Abf,
    const unsigned short* __restrict__ Bbf,
    float* __restrict__ C, float* __restrict__ bnpart,
    int M, int N, int K)
{
    constexpr int WM = BM / 2, WN = BN / 2;
    constexpr int MI = WM / 16, NI = WN / 16;
    constexpr int GA = (BM * BK) / 2048;
    constexpr int GB = (BN * BK) / 2048;

    __shared__ unsigned short As[2][BM * BK];
    __shared__ unsigned short Bs[2][BN * BK];

    const int tid  = threadIdx.x;
    const int lane = tid & 63;
    const int wid  = tid >> 6;
    const int wr   = wid >> 1;
    const int wc   = wid & 1;
    const int m0   = blockIdx.y * BM;
    const int n0   = blockIdx.x * BN;   // fast dim: XCD = n-block%8
    const int fr   = lane & 15;
    const int kq   = lane >> 4;

    f32x4 acc[MI][NI] = {};

    auto stage = [&](int bs, int k0) {
#pragma unroll
        for (int r = 0; r < GA; r++) {
            const int e   = r * 2048 + tid * 8;
            const int row = e / BK;
            const int swz = ((((e % BK) >> 3) ^ (row & 7)) << 3);
            gl_lds16(Abf + (size_t)(m0 + row) * K + k0 + swz, &As[bs][e]);
        }
#pragma unroll
        for (int r = 0; r < GB; r++) {
            const int e   = r * 2048 + tid * 8;
            const int row = e / BK;
            const int swz = ((((e % BK) >> 3) ^ (row & 7)) << 3);
            gl_lds16(Bbf + (size_t)(n0 + row) * K + k0 + swz, &Bs[bs][e]);
        }
    };
    auto compute = [&](int bs) {
#pragma unroll
        for (int kh = 0; kh < BK / 32; kh++) {
            const int kchunk = kh * 4 + kq;
            bf16x8 af[MI], bfv[NI];
#pragma unroll
            for (int i = 0; i < MI; i++) {
                const int row = wr * WM + i * 16 + fr;
                af[i] = *(const bf16x8*)&As[bs][row * BK
                        + ((kchunk ^ (row & 7)) << 3)];
            }
#pragma unroll
            for (int j = 0; j < NI; j++) {
                const int row = wc * WN + j * 16 + fr;
                bfv[j] = *(const bf16x8*)&Bs[bs][row * BK
                         + ((kchunk ^ (row & 7)) << 3)];
            }
#pragma unroll
            for (int i = 0; i < MI; i++)
#pragma unroll
                for (int j = 0; j < NI; j++)
                    acc[i][j] = __builtin_amdgcn_mfma_f32_16x16x32_bf16(
                        af[i], bfv[j], acc[i][j], 0, 0, 0);
        }
    };

    stage(0, 0);
    __syncthreads();

    const int NT = K / BK;
    int cur = 0;
    for (int t = 0; t < NT - 1; t++) {
        stage(cur ^ 1, (t + 1) * BK);   // DMA into other buffer
        compute(cur);                   // MFMA covers DMA latency
        __syncthreads();
        cur ^= 1;
    }
    compute(cur);

    const int row0 = m0 + wr * WM + (kq << 2);
    const int col0 = n0 + wc * WN + fr;
#pragma unroll
    for (int j = 0; j < NI; j++) {
        const int cc = col0 + j * 16;
#pragma unroll
        for (int i = 0; i < MI; i++)
#pragma unroll
            for (int r = 0; r < 4; r++)
                C[(size_t)(row0 + i * 16 + r) * N + cc] = acc[i][j][r];
    }

    if (BNP && n0 >= NDIM) {
        float s = 0.f, ss = 0.f;
#pragma unroll
        for (int i = 0; i < MI; i++)
#pragma unroll
            for (int j = 0; j < NI; j++)
#pragma unroll
                for (int r = 0; r < 4; r++) {
                    const float v = acc[i][j][r];
                    s += v;
                    ss = fmaf(v, v, ss);
                }
#pragma unroll
        for (int off = 32; off; off >>= 1) {
            s  += __shfl_down(s, off);
            ss += __shfl_down(ss, off);
        }
        __shared__ float rs[4], rss[4];
        if (lane == 0) { rs[wid] = s; rss[wid] = ss; }
        __syncthreads();
        if (tid == 0)
            ((float2*)bnpart)[((n0 - NDIM) >> 6) * 8 + (m0 >> 6)] =
                make_float2(rs[0] + rs[1] + rs[2] + rs[3],
                            rss[0] + rss[1] + rss[2] + rss[3]);
    }
}

// ---------------- bf16-MFMA GEMM, in-kernel f32->bf16 B staging --------
// (r13 g2, unchanged: A bf16 via gl_lds, B=Wout f32 reg-staged)
template<int BM, int BN, int BK>
__global__ __launch_bounds__(256) void gemm_f(
    const unsigned short* __restrict__ Abf, const float* __restrict__ Bf,
    float* __restrict__ C, const float* __restrict__ bias,
    int M, int N, int K)
{
    constexpr int WM = BM / 2, WN = BN / 2;
    constexpr int MI = WM / 16, NI = WN / 16;
    constexpr int CPR = BK / 8;
    constexpr int GA = (BM * BK) / 2048;
    constexpr int RB = (BN * BK) / 8 / 256;

    __shared__ unsigned short As[2][BM * BK];
    __shared__ unsigned short Bs[2][BN * BK];

    const int tid  = threadIdx.x;
    const int lane = tid & 63;
    const int wid  = tid >> 6;
    const int wr   = wid >> 1;
    const int wc   = wid & 1;
    const int m0   = blockIdx.y * BM;
    const int n0   = blockIdx.x * BN;
    const int fr   = lane & 15;
    const int kq   = lane >> 4;

    f32x4 acc[MI][NI] = {};
    float4 rgb[RB][2];

    auto load_A = [&](int bs, int k0) {
#pragma unroll
        for (int r = 0; r < GA; r++) {
            const int e   = r * 2048 + tid * 8;
            const int row = e / BK;
            const int swz = ((((e % BK) >> 3) ^ (row & 7)) << 3);
            gl_lds16(Abf + (size_t)(m0 + row) * K + k0 + swz, &As[bs][e]);
        }
    };
    auto load_B = [&](int k0) {
#pragma unroll
        for (int r = 0; r < RB; r++) {
            const int idx = r * 256 + tid;
            const int row = idx / CPR, cc = idx % CPR;
            const float4* g = (const float4*)(Bf + (size_t)(n0 + row) * K
                                              + k0 + cc * 8);
            rgb[r][0] = g[0];
            rgb[r][1] = g[1];
        }
    };
    auto write_B = [&](int bs) {
#pragma unroll
        for (int r = 0; r < RB; r++) {
            const int idx = r * 256 + tid;
            const int row = idx / CPR, cc = idx % CPR;
            bf16x8 v;
            v[0] = (__bf16)rgb[r][0].x; v[1] = (__bf16)rgb[r][0].y;
            v[2] = (__bf16)rgb[r][0].z; v[3] = (__bf16)rgb[r][0].w;
            v[4] = (__bf16)rgb[r][1].x; v[5] = (__bf16)rgb[r][1].y;
            v[6] = (__bf16)rgb[r][1].z; v[7] = (__bf16)rgb[r][1].w;
            *(bf16x8*)&Bs[bs][row * BK + ((cc ^ (row & 7)) << 3)] = v;
        }
    };
    auto compute = [&](int bs) {
#pragma unroll
        for (int kh = 0; kh < BK / 32; kh++) {
            const int kchunk = kh * 4 + kq;
            bf16x8 af[MI], bfv[NI];
#pragma unroll
            for (int i = 0; i < MI; i++) {
                const int row = wr * WM + i * 16 + fr;
                af[i] = *(const bf16x8*)&As[bs][row * BK
                        + ((kchunk ^ (row & 7)) << 3)];
            }
#pragma unroll
            for (int j = 0; j < NI; j++) {
                const int row = wc * WN + j * 16 + fr;
                bfv[j] = *(const bf16x8*)&Bs[bs][row * BK
                         + ((kchunk ^ (row & 7)) << 3)];
            }
#pragma unroll
            for (int i = 0; i < MI; i++)
#pragma unroll
                for (int j = 0; j < NI; j++)
                    acc[i][j] = __builtin_amdgcn_mfma_f32_16x16x32_bf16(
                        af[i], bfv[j], acc[i][j], 0, 0, 0);
        }
    };

    load_A(0, 0);
    load_B(0);
    write_B(0);
    __syncthreads();

    const int NT = K / BK;
    int cur = 0;
    for (int t = 0; t < NT - 1; t++) {
        load_A(cur ^ 1, (t + 1) * BK);
        load_B((t + 1) * BK);
        compute(cur);
        write_B(cur ^ 1);
        __syncthreads();
        cur ^= 1;
    }
    compute(cur);

    const int row0 = m0 + wr * WM + (kq << 2);
    const int col0 = n0 + wc * WN + fr;
#pragma unroll
    for (int j = 0; j < NI; j++) {
        const int cc = col0 + j * 16;
        const float badd = bias[cc];
#pragma unroll
        for (int i = 0; i < MI; i++)
#pragma unroll
            for (int r = 0; r < 4; r++)
                C[(size_t)(row0 + i * 16 + r) * N + cc] = acc[i][j][r] + badd;
    }
}

// ---------------- fused BN-final + outer-product + softmax + PV --------
// Single-pass no-max softmax (|logit| <~ 30 << 88). All 16 bias float4
// in flight upfront; lanes 0-15 reduce the head's 16 BN partials.
__global__ __launch_bounds__(256) void attn_k(
    const float* __restrict__ qv, const float* __restrict__ kparam,
    const float* __restrict__ bias, const float* __restrict__ temperature,
    const float* __restrict__ bnpart, const float* __restrict__ gamma,
    const float* __restrict__ beta, unsigned short* __restrict__ aout)
{
    const int bh = blockIdx.x;
    const int b  = bh >> 4;
    const int h  = bh & 15;
    const int tid = threadIdx.x;

    __shared__ float ks[NCPH], vsr[NCPH], s2sh[2];
    if (tid < 32)
        ((float4*)ks)[tid] =
            ((const float4*)(kparam + (size_t)b * NDIM + h * NCPH))[tid];
    else if (tid < 64)
        ((float4*)vsr)[tid - 32] =
            ((const float4*)(qv + (size_t)b * (2 * NDIM) + NDIM + h * NCPH))[tid - 32];

    if (tid < 16) {
        float2 p = ((const float2*)bnpart)[(h * 2 + (tid >> 3)) * 8 + (tid & 7)];
        float s = p.x, ss = p.y;
#pragma unroll
        for (int off = 8; off; off >>= 1) {
            s  += __shfl_xor(s, off);
            ss += __shfl_xor(ss, off);
        }
        if (tid == 0) {
            const float inv = 1.0f / (NBATCH * NCPH);
            float mean = s * inv;
            float var  = ss * inv - mean * mean;
            float sc   = gamma[h] * rsqrtf(var + 1e-5f);
            s2sh[0] = sc;
            s2sh[1] = beta[h] - mean * sc;
        }
    }

    const int c = tid >> 1, half = tid & 1;
    const float qc   = qv[(size_t)b * (2 * NDIM) + h * NCPH + c];
    const float temp = temperature[h];

    const float4* bp = (const float4*)(bias + ((size_t)bh << 14)
                                       + (size_t)c * NCPH + half * 64);
    float4 l4[16];
#pragma unroll
    for (int j = 0; j < 16; j++) l4[j] = bp[j];

    __syncthreads();
    const float sc = s2sh[0], sh = s2sh[1];
    const float4* kk4 = (const float4*)(ks  + half * 64);
    const float4* vv4 = (const float4*)(vsr + half * 64);

    float s0 = 0.f, s1 = 0.f, o0 = 0.f, o1 = 0.f;
#pragma unroll
    for (int j = 0; j < 16; j++) {
        const float4 bb = l4[j];
        const float4 kx = kk4[j];
        const float4 vx = vv4[j];
        float px = __expf(fmaf(qc, kx.x, bb.x) * temp);
        float py = __expf(fmaf(qc, kx.y, bb.y) * temp);
        float pz = __expf(fmaf(qc, kx.z, bb.z) * temp);
        float pw = __expf(fmaf(qc, kx.w, bb.w) * temp);
        s0 += px; s1 += py; s0 += pz; s1 += pw;
        o0 = fmaf(px, vx.x, o0);
        o1 = fmaf(py, vx.y, o1);
        o0 = fmaf(pz, vx.z, o0);
        o1 = fmaf(pw, vx.w, o1);
    }
    float s = s0 + s1, o = o0 + o1;
    s += __shfl_xor(s, 1);
    o += __shfl_xor(o, 1);

    if (half == 0)
        aout[(size_t)b * NDIM + h * NCPH + c] = f2bf(fmaf(sc, o / s, sh));
}

// ------------------------------ launch ---------------------------------
extern "C" void kernel_launch(void* const* d_in, const int* in_sizes, int n_in,
                              void* d_out, int out_size, void* d_ws, size_t ws_size,
                              hipStream_t stream)
{
    const float* x      = (const float*)d_in[0];
    const float* Wqv    = (const float*)d_in[1];
    const float* temp   = (const float*)d_in[2];
    const float* kparam = (const float*)d_in[3];
    const float* bias   = (const float*)d_in[4];
    const float* gamma  = (const float*)d_in[5];
    const float* beta   = (const float*)d_in[6];
    const float* Wout   = (const float*)d_in[7];
    const float* bout   = (const float*)d_in[8];
    float* out = (float*)d_out;

    char* ws = (char*)d_ws;
    float*          qv     = (float*)(ws);                      //  8 MiB
    unsigned short* ao_bf  = (unsigned short*)(ws + 8388608);   //  2 MiB
    float*          bnpart = (float*)(ws + 10485760);           //  2 KiB
    unsigned short* wqv_bf = (unsigned short*)(ws + 10487808);  // 16 MiB
    unsigned short* x_bf   = (unsigned short*)(ws + 27265024);  //  2 MiB

    // Wqv + x -> bf16 (9216 blocks)
    cvt_wx<<<9216, 256, 0, stream>>>(Wqv, x, wqv_bf, x_bf);

    // qv = x @ W_qv^T : M=512, N=4096, K=2048 (512 blocks, pure-DMA, BK=128)
    gemm_dma<64, 64, 128, true><<<dim3(64, 8), 256, 0, stream>>>(
        x_bf, wqv_bf, qv, bnpart, NBATCH, 2 * NDIM, NDIM);

    attn_k<<<NBATCH * NHEADS, 256, 0, stream>>>(
        qv, kparam, bias, temp, bnpart, gamma, beta, ao_bf);

    // out = attn_out @ W_out^T + b_out : M=512, N=2048, K=2048 (BK=128)
    gemm_f<64, 32, 128><<<dim3(64, 8), 256, 0, stream>>>(
        ao_bf, Wout, out, bout, NBATCH, NDIM, NDIM);
}